// Round 9
// baseline (24102.603 us; speedup 1.0000x reference)
//
#include <hip/hip_runtime.h>
#include <math.h>

// MGU: f = sigmoid(xf_t + h Wfh^T + bfh); h' = (1-f)h + f*tanh((f*h) Whf^T + bhf + xh_t)
// Phase 1 (parallel): XF = x Wfx^T + bfx + bfh ; XH = x Whx^T + bhx + bhf
// Phase 2 (sequential): persistent cooperative scan, recurrent weights in LDS.
//
// r8 sync protocol (root-cause fix): publish via atomic EXCHANGE (RMW executes
// AT the LLC coherence point -> no dirty line left in producer's non-coherent
// L2 -> remote reads need no probe). Ordering without fences:
//   payload atomicExch (returning form kept alive) -> __syncthreads (compiler
//   drains vmcnt(0) before s_barrier => RMWs have executed at LLC) -> flag
//   atomicExch. Readers: ONE wave polls the 1KB per-wg flag board (16 lines,
//   branch-free), then all threads bulk-read the clean 8KB payload once.
// History: r2 fences=L2 flush (41us/step); r3 serialized payload polls (8.7);
// r4 hot-spin congestion (9.4, 1.0GB); r5 flag board w/ race+serial straggler
// (10.8); r6 backoff cascade (10.0, 1.2GB). Poll traffic ~ time => cut polls
// 16x and eliminate probes.

#define S_LEN 2048
#define HDIM  2048
#define DDIM  2048
#define NWG   256      // scan workgroups (= CU count; 1 wg/CU due to 144 KiB LDS)
#define ROWS  8        // output rows owned per wg (256*8 = 2048)
#define SCAN_BLK 256   // 4 waves
#define QELEM (HDIM / SCAN_BLK)   // 8 payload f32 per thread

// ---------------------------------------------------------------------------
// GEMM: out[s,h] = sum_d x[s,d] * W[h,d] + b1[h] + b2[h]   (biases folded)
// ---------------------------------------------------------------------------
__global__ __launch_bounds__(256) void xproj_gemm(
    const float* __restrict__ x,
    const float* __restrict__ Wfx, const float* __restrict__ bfx, const float* __restrict__ bfh,
    const float* __restrict__ Whx, const float* __restrict__ bhx, const float* __restrict__ bhf,
    float* __restrict__ XF, float* __restrict__ XH)
{
    const float* W  = blockIdx.z ? Whx : Wfx;
    const float* b1 = blockIdx.z ? bhx : bfx;
    const float* b2 = blockIdx.z ? bhf : bfh;
    float* out      = blockIdx.z ? XH  : XF;

    __shared__ float As[16][64];   // [k][s]
    __shared__ float Bs[16][64];   // [k][h]

    const int tid = threadIdx.x;
    const int s0 = blockIdx.y * 64;
    const int h0 = blockIdx.x * 64;
    const int lr = tid >> 2;
    const int lk = (tid & 3) << 2;
    const int ty = tid >> 4;
    const int tx = tid & 15;

    float acc[4][4];
#pragma unroll
    for (int i = 0; i < 4; ++i)
#pragma unroll
        for (int j = 0; j < 4; ++j) acc[i][j] = 0.f;

    for (int k0 = 0; k0 < DDIM; k0 += 16) {
        float4 av = *(const float4*)&x[(size_t)(s0 + lr) * DDIM + k0 + lk];
        float4 bv = *(const float4*)&W[(size_t)(h0 + lr) * DDIM + k0 + lk];
        As[lk + 0][lr] = av.x; As[lk + 1][lr] = av.y; As[lk + 2][lr] = av.z; As[lk + 3][lr] = av.w;
        Bs[lk + 0][lr] = bv.x; Bs[lk + 1][lr] = bv.y; Bs[lk + 2][lr] = bv.z; Bs[lk + 3][lr] = bv.w;
        __syncthreads();
#pragma unroll
        for (int kk = 0; kk < 16; ++kk) {
            float4 a4 = *(const float4*)&As[kk][ty << 2];
            float4 b4 = *(const float4*)&Bs[kk][tx << 2];
            float ar[4] = {a4.x, a4.y, a4.z, a4.w};
            float br[4] = {b4.x, b4.y, b4.z, b4.w};
#pragma unroll
            for (int i = 0; i < 4; ++i)
#pragma unroll
                for (int j = 0; j < 4; ++j)
                    acc[i][j] = fmaf(ar[i], br[j], acc[i][j]);
        }
        __syncthreads();
    }

    float4 bv1 = *(const float4*)&b1[h0 + (tx << 2)];
    float4 bv2 = *(const float4*)&b2[h0 + (tx << 2)];
    float bb[4] = {bv1.x + bv2.x, bv1.y + bv2.y, bv1.z + bv2.z, bv1.w + bv2.w};
#pragma unroll
    for (int i = 0; i < 4; ++i) {
        int s = s0 + (ty << 2) + i;
        float4 o;
        o.x = acc[i][0] + bb[0];
        o.y = acc[i][1] + bb[1];
        o.z = acc[i][2] + bb[2];
        o.w = acc[i][3] + bb[3];
        *(float4*)&out[(size_t)s * HDIM + h0 + (tx << 2)] = o;
    }
}

// ---------------------------------------------------------------------------
// Sync primitives: RMW publish (executes at LLC), flag-board poll.
// ---------------------------------------------------------------------------
__device__ __forceinline__ void publish_rmw(float* buf, int idx, float v)
{
    float old = __hip_atomic_exchange(&buf[idx], v,
                                      __ATOMIC_RELAXED, __HIP_MEMORY_SCOPE_AGENT);
    asm volatile("" :: "v"(old));   // keep returning form; vmcnt tracks completion
}

// One wave polls all NWG per-wg flags (4/lane, branch-free, 16 cache lines).
// Flags are monotone and cannot pass `target` while any wg still polls it
// (epoch dependency chain), so == is exact. 0xAA poison never matches.
__device__ __forceinline__ void poll_flags(const unsigned* flags, unsigned target,
                                           int lane, int& bail)
{
    if (bail) return;
    int guard = 0;
    for (;;) {
        unsigned v0 = __hip_atomic_load(&flags[lane],       __ATOMIC_RELAXED, __HIP_MEMORY_SCOPE_AGENT);
        unsigned v1 = __hip_atomic_load(&flags[lane + 64],  __ATOMIC_RELAXED, __HIP_MEMORY_SCOPE_AGENT);
        unsigned v2 = __hip_atomic_load(&flags[lane + 128], __ATOMIC_RELAXED, __HIP_MEMORY_SCOPE_AGENT);
        unsigned v3 = __hip_atomic_load(&flags[lane + 192], __ATOMIC_RELAXED, __HIP_MEMORY_SCOPE_AGENT);
        int ok = (v0 == target) & (v1 == target) & (v2 == target) & (v3 == target);
        if (__all(ok)) break;
        if (++guard > (1 << 18)) { bail = 1; break; }
        if (guard > 4) __builtin_amdgcn_s_sleep(2);   // mild pacing only
    }
}

// All threads: one branch-free bulk read of the (now guaranteed-fresh) payload
// into LDS. Atomic loads so stale local-L2 copies are bypassed.
__device__ __forceinline__ void bulk_read(const float* pay, float* lds, int tid)
{
    float v[QELEM];
#pragma unroll
    for (int q = 0; q < QELEM; ++q)
        v[q] = __hip_atomic_load(&pay[tid + q * SCAN_BLK],
                                 __ATOMIC_RELAXED, __HIP_MEMORY_SCOPE_AGENT);
#pragma unroll
    for (int q = 0; q < QELEM; ++q)
        lds[tid + q * SCAN_BLK] = v[q];
}

// ---------------------------------------------------------------------------
// Persistent cooperative scan. wg w owns rows [8w, 8w+8) of Wfh and Whf (LDS);
// its 8 payload floats are one 32B half-line; its flag is 1 u32.
// Epochs: h0 flag=1; step t waits hflag==t+1, publishes gflag=t+1, waits
// gflag==t+1, publishes hflag=t+2.
// Publish ordering (NO fences): payload atomicExch -> __syncthreads (drains
// vmcnt => RMW done at LLC) -> flag atomicExch.
// Overwrite-safety: wg A writes h_pay epoch t+2 only after observing
// gflag==t+1 from ALL wgs, which requires every wg to have completed its
// bulk_read of h epoch t+1. Single-buffer is race-free.
// ---------------------------------------------------------------------------
__global__ __launch_bounds__(SCAN_BLK) void mgu_scan(
    const float* __restrict__ h0,
    const float* __restrict__ Wfh,
    const float* __restrict__ Whf,
    const float* __restrict__ XF,
    const float* __restrict__ XH,
    float* __restrict__ y,
    float* __restrict__ hfin,
    float* h_pay, float* g_pay,
    unsigned* hflag, unsigned* gflag)
{
    extern __shared__ float smem[];
    float* wf    = smem;                     // ROWS*HDIM (Wfh rows)
    float* wh    = wf + ROWS * HDIM;         // ROWS*HDIM (Whf rows)
    float* h_lds = wh + ROWS * HDIM;         // HDIM
    float* g_lds = h_lds + HDIM;             // HDIM

    const int wg   = blockIdx.x;
    const int tid  = threadIdx.x;
    const int lane = tid & 63;
    const int wv   = tid >> 6;               // wave 0..3
    const int base = wg * ROWS;

    // ---- one-time: stage this wg's weight rows into LDS
    for (int i = tid; i < ROWS * HDIM / 4; i += SCAN_BLK) {
        ((float4*)wf)[i] = ((const float4*)(Wfh + (size_t)base * HDIM))[i];
        ((float4*)wh)[i] = ((const float4*)(Whf + (size_t)base * HDIM))[i];
    }
    // ---- publish this wg's h0 slice, then its flag (epoch 1)
    if (tid < ROWS)
        publish_rmw(h_pay, base + tid, h0[base + tid]);
    __syncthreads();                          // drains vmcnt: payload at LLC
    if (tid == 0)
        (void)__hip_atomic_exchange(&hflag[wg], 1u,
                                    __ATOMIC_RELAXED, __HIP_MEMORY_SCOPE_AGENT);

    const int r0 = wv * 2, r1 = wv * 2 + 1;  // this wave's rows (of ROWS)
    int bail = 0;

    for (int t = 0; t < S_LEN; ++t) {
        // per-row step constants (issued before the waits -> overlapped)
        float xf0 = XF[(size_t)t * HDIM + base + r0];
        float xf1 = XF[(size_t)t * HDIM + base + r1];
        float xh0 = XH[(size_t)t * HDIM + base + r0];
        float xh1 = XH[(size_t)t * HDIM + base + r1];

        // ---- phase A: wave0 polls h flag board; all bulk-read h payload
        if (wv == 0) poll_flags(hflag, (unsigned)(t + 1), lane, bail);
        __syncthreads();
        bulk_read(h_pay, h_lds, tid);
        __syncthreads();

        // ---- matvec1: f rows
        float4 a0 = {0, 0, 0, 0}, a1 = {0, 0, 0, 0};
#pragma unroll
        for (int it = 0; it < HDIM / 256; ++it) {
            int j = it * 256 + (lane << 2);
            float4 hv = *(const float4*)&h_lds[j];
            float4 w0 = *(const float4*)&wf[r0 * HDIM + j];
            float4 w1 = *(const float4*)&wf[r1 * HDIM + j];
            a0.x = fmaf(w0.x, hv.x, a0.x); a0.y = fmaf(w0.y, hv.y, a0.y);
            a0.z = fmaf(w0.z, hv.z, a0.z); a0.w = fmaf(w0.w, hv.w, a0.w);
            a1.x = fmaf(w1.x, hv.x, a1.x); a1.y = fmaf(w1.y, hv.y, a1.y);
            a1.z = fmaf(w1.z, hv.z, a1.z); a1.w = fmaf(w1.w, hv.w, a1.w);
        }
        float s0 = (a0.x + a0.y) + (a0.z + a0.w);
        float s1 = (a1.x + a1.y) + (a1.z + a1.w);
#pragma unroll
        for (int m = 32; m >= 1; m >>= 1) {
            s0 += __shfl_xor(s0, m);
            s1 += __shfl_xor(s1, m);
        }
        float f0 = 0.f, f1 = 0.f, ho0 = 0.f, ho1 = 0.f;
        if (lane == 0) {
            f0 = 1.f / (1.f + expf(-(s0 + xf0)));
            f1 = 1.f / (1.f + expf(-(s1 + xf1)));
            ho0 = h_lds[base + r0];              // register-cache h_old
            ho1 = h_lds[base + r1];
            publish_rmw(g_pay, base + r0, f0 * ho0);
            publish_rmw(g_pay, base + r1, f1 * ho1);
        }
        __syncthreads();                          // drains vmcnt: g at LLC
        if (tid == 0)
            (void)__hip_atomic_exchange(&gflag[wg], (unsigned)(t + 1),
                                        __ATOMIC_RELAXED, __HIP_MEMORY_SCOPE_AGENT);

        // ---- phase B: wave0 polls g flag board; all bulk-read g payload
        if (wv == 0) poll_flags(gflag, (unsigned)(t + 1), lane, bail);
        __syncthreads();
        bulk_read(g_pay, g_lds, tid);
        __syncthreads();

        // ---- matvec2: candidate rows
        a0 = make_float4(0, 0, 0, 0); a1 = make_float4(0, 0, 0, 0);
#pragma unroll
        for (int it = 0; it < HDIM / 256; ++it) {
            int j = it * 256 + (lane << 2);
            float4 gv = *(const float4*)&g_lds[j];
            float4 w0 = *(const float4*)&wh[r0 * HDIM + j];
            float4 w1 = *(const float4*)&wh[r1 * HDIM + j];
            a0.x = fmaf(w0.x, gv.x, a0.x); a0.y = fmaf(w0.y, gv.y, a0.y);
            a0.z = fmaf(w0.z, gv.z, a0.z); a0.w = fmaf(w0.w, gv.w, a0.w);
            a1.x = fmaf(w1.x, gv.x, a1.x); a1.y = fmaf(w1.y, gv.y, a1.y);
            a1.z = fmaf(w1.z, gv.z, a1.z); a1.w = fmaf(w1.w, gv.w, a1.w);
        }
        s0 = (a0.x + a0.y) + (a0.z + a0.w);
        s1 = (a1.x + a1.y) + (a1.z + a1.w);
#pragma unroll
        for (int m = 32; m >= 1; m >>= 1) {
            s0 += __shfl_xor(s0, m);
            s1 += __shfl_xor(s1, m);
        }
        if (lane == 0) {
            float hh0 = tanhf(s0 + xh0);
            float hh1 = tanhf(s1 + xh1);
            float hn0 = ho0 + f0 * (hh0 - ho0);   // (1-f)h + f*hhat
            float hn1 = ho1 + f1 * (hh1 - ho1);
            y[(size_t)t * HDIM + base + r0] = hn0;
            y[(size_t)t * HDIM + base + r1] = hn1;
            publish_rmw(h_pay, base + r0, hn0);
            publish_rmw(h_pay, base + r1, hn1);
            if (t == S_LEN - 1) {
                hfin[base + r0] = hn0;
                hfin[base + r1] = hn1;
            }
        }
        __syncthreads();                          // drains vmcnt: h' at LLC
        if (tid == 0)
            (void)__hip_atomic_exchange(&hflag[wg], (unsigned)(t + 2),
                                        __ATOMIC_RELAXED, __HIP_MEMORY_SCOPE_AGENT);
    }
}

// ---------------------------------------------------------------------------
extern "C" void kernel_launch(void* const* d_in, const int* in_sizes, int n_in,
                              void* d_out, int out_size, void* d_ws, size_t ws_size,
                              hipStream_t stream)
{
    const float* x   = (const float*)d_in[0];
    const float* h0  = (const float*)d_in[1];
    const float* Wfx = (const float*)d_in[2];
    const float* bfx = (const float*)d_in[3];
    const float* Wfh = (const float*)d_in[4];
    const float* bfh = (const float*)d_in[5];
    const float* Whf = (const float*)d_in[6];
    const float* bhf = (const float*)d_in[7];
    const float* Whx = (const float*)d_in[8];
    const float* bhx = (const float*)d_in[9];

    float* y    = (float*)d_out;
    float* hfin = y + (size_t)S_LEN * HDIM;

    // workspace layout (flags self-validate vs 0xAA poison -> no memset)
    float* XF       = (float*)d_ws;
    float* XH       = XF + (size_t)S_LEN * HDIM;
    float* h_pay    = XH + (size_t)S_LEN * HDIM;
    float* g_pay    = h_pay + HDIM;
    unsigned* hflag = (unsigned*)(g_pay + HDIM);
    unsigned* gflag = hflag + NWG;

    // phase 1: input projections (biases folded: XF += bfx+bfh, XH += bhx+bhf)
    dim3 gg(HDIM / 64, S_LEN / 64, 2);
    xproj_gemm<<<gg, 256, 0, stream>>>(x, Wfx, bfx, bfh, Whx, bhx, bhf, XF, XH);

    // phase 2: cooperative persistent scan (144 KiB dynamic LDS -> 1 wg/CU)
    const int smem_bytes = (2 * ROWS * HDIM + 2 * HDIM) * (int)sizeof(float); // 147456
    hipFuncSetAttribute((const void*)mgu_scan,
                        hipFuncAttributeMaxDynamicSharedMemorySize, smem_bytes);

    void* args[] = {(void*)&h0, (void*)&Wfh, (void*)&Whf, (void*)&XF, (void*)&XH,
                    (void*)&y, (void*)&hfin, (void*)&h_pay, (void*)&g_pay,
                    (void*)&hflag, (void*)&gflag};
    hipError_t err = hipLaunchCooperativeKernel((void*)mgu_scan, dim3(NWG), dim3(SCAN_BLK),
                                                args, (unsigned)smem_bytes, stream);
    if (err != hipSuccess) {
        // fallback: plain launch (grid == CU count, 1 wg/CU -> co-resident;
        // bail guards prevent a hard hang if co-residency fails)
        mgu_scan<<<dim3(NWG), dim3(SCAN_BLK), smem_bytes, stream>>>(
            h0, Wfh, Whf, XF, XH, y, hfin, h_pay, g_pay, hflag, gflag);
    }
}

// Round 10
// 21525.406 us; speedup vs baseline: 1.1197x; 1.1197x over previous
//
#include <hip/hip_runtime.h>
#include <math.h>

// MGU: f = sigmoid(xf_t + h Wfh^T + bfh); h' = (1-f)h + f*tanh((f*h) Whf^T + bhf + xh_t)
// Phase 1 (parallel): XF = x Wfx^T + bfx + bfh ; XH = x Whx^T + bhx + bhf
// Phase 2 (sequential): persistent cooperative scan, recurrent weights in LDS.
// Exchange = r3's SELF-VALIDATING TAGGED WORDS (epoch<<32|f32), relaxed agent
// atomics, NO fences, plain-store publish.
// r10 change: SCAN_BLK 256 -> 1024. Each thread polls 2 elements (not 8):
// the serialized poll chain (8 dependent LLC RTTs, ~1.5-3us of the measured
// 4.3us/phase) shrinks 4x. Matvec split 2 waves/row with LDS partial combine.
// Protocol scoreboard (us/step): r3 tagged+sleep 8.7 BEST; r4 hotspin 9.4;
// r6 backoff 10.0; r5 flagboard 10.8; r8 RMW+flags 11.4 (FETCH lowest, time
// worst -> traffic was symptom; RMW serialized 2 extra LLC RTTs into path).

#define S_LEN 2048
#define HDIM  2048
#define DDIM  2048
#define NWG   256       // scan wgs (= CU count; 1 wg/CU due to 144 KiB LDS)
#define ROWS  8         // output rows owned per wg (256*8 = 2048)
#define SCAN_BLK 1024   // 16 waves
#define QELEM (HDIM / SCAN_BLK)   // 2 tagged elements gathered per thread

typedef unsigned long long ull;

// ---------------------------------------------------------------------------
// GEMM: out[s,h] = sum_d x[s,d] * W[h,d] + b1[h] + b2[h]   (biases folded)
// ---------------------------------------------------------------------------
__global__ __launch_bounds__(256) void xproj_gemm(
    const float* __restrict__ x,
    const float* __restrict__ Wfx, const float* __restrict__ bfx, const float* __restrict__ bfh,
    const float* __restrict__ Whx, const float* __restrict__ bhx, const float* __restrict__ bhf,
    float* __restrict__ XF, float* __restrict__ XH)
{
    const float* W  = blockIdx.z ? Whx : Wfx;
    const float* b1 = blockIdx.z ? bhx : bfx;
    const float* b2 = blockIdx.z ? bhf : bfh;
    float* out      = blockIdx.z ? XH  : XF;

    __shared__ float As[16][64];   // [k][s]
    __shared__ float Bs[16][64];   // [k][h]

    const int tid = threadIdx.x;
    const int s0 = blockIdx.y * 64;
    const int h0 = blockIdx.x * 64;
    const int lr = tid >> 2;
    const int lk = (tid & 3) << 2;
    const int ty = tid >> 4;
    const int tx = tid & 15;

    float acc[4][4];
#pragma unroll
    for (int i = 0; i < 4; ++i)
#pragma unroll
        for (int j = 0; j < 4; ++j) acc[i][j] = 0.f;

    for (int k0 = 0; k0 < DDIM; k0 += 16) {
        float4 av = *(const float4*)&x[(size_t)(s0 + lr) * DDIM + k0 + lk];
        float4 bv = *(const float4*)&W[(size_t)(h0 + lr) * DDIM + k0 + lk];
        As[lk + 0][lr] = av.x; As[lk + 1][lr] = av.y; As[lk + 2][lr] = av.z; As[lk + 3][lr] = av.w;
        Bs[lk + 0][lr] = bv.x; Bs[lk + 1][lr] = bv.y; Bs[lk + 2][lr] = bv.z; Bs[lk + 3][lr] = bv.w;
        __syncthreads();
#pragma unroll
        for (int kk = 0; kk < 16; ++kk) {
            float4 a4 = *(const float4*)&As[kk][ty << 2];
            float4 b4 = *(const float4*)&Bs[kk][tx << 2];
            float ar[4] = {a4.x, a4.y, a4.z, a4.w};
            float br[4] = {b4.x, b4.y, b4.z, b4.w};
#pragma unroll
            for (int i = 0; i < 4; ++i)
#pragma unroll
                for (int j = 0; j < 4; ++j)
                    acc[i][j] = fmaf(ar[i], br[j], acc[i][j]);
        }
        __syncthreads();
    }

    float4 bv1 = *(const float4*)&b1[h0 + (tx << 2)];
    float4 bv2 = *(const float4*)&b2[h0 + (tx << 2)];
    float bb[4] = {bv1.x + bv2.x, bv1.y + bv2.y, bv1.z + bv2.z, bv1.w + bv2.w};
#pragma unroll
    for (int i = 0; i < 4; ++i) {
        int s = s0 + (ty << 2) + i;
        float4 o;
        o.x = acc[i][0] + bb[0];
        o.y = acc[i][1] + bb[1];
        o.z = acc[i][2] + bb[2];
        o.w = acc[i][3] + bb[3];
        *(float4*)&out[(size_t)s * HDIM + h0 + (tx << 2)] = o;
    }
}

// ---------------------------------------------------------------------------
// Tagged publish / gather (NO fences; relaxed agent atomics, plain stores).
// ---------------------------------------------------------------------------
__device__ __forceinline__ void publish_tagged(ull* buf, int idx, unsigned epoch, float v)
{
    ull w = ((ull)epoch << 32) | (ull)__float_as_uint(v);
    __hip_atomic_store(&buf[idx], w, __ATOMIC_RELAXED, __HIP_MEMORY_SCOPE_AGENT);
}

// Each thread gathers its 2 tagged elements (tid, tid+1024): both loads issued
// back-to-back (1 overlapped LLC RTT per round, vs r3's 8 serialized), commit
// to LDS per element as tags match, s_sleep(1) pacing on idle rounds.
// Tags are monotone and cannot pass `target` until every wg completes this
// gather (epoch dependency chain), so == is exact; re-reads are idempotent.
// Ends with __syncthreads(). `bail` guard prevents a hard hang (wrong-fast).
__device__ __forceinline__ void gather_tagged(const ull* buf, unsigned target,
                                              float* lds, int tid, int& bail)
{
    if (!bail) {
        int guard = 0;
        unsigned done = 0;
        for (;;) {
            ull w0 = __hip_atomic_load(&buf[tid],            __ATOMIC_RELAXED, __HIP_MEMORY_SCOPE_AGENT);
            ull w1 = __hip_atomic_load(&buf[tid + SCAN_BLK], __ATOMIC_RELAXED, __HIP_MEMORY_SCOPE_AGENT);
            if ((unsigned)(w0 >> 32) == target) { lds[tid]            = __uint_as_float((unsigned)w0); done |= 1u; }
            if ((unsigned)(w1 >> 32) == target) { lds[tid + SCAN_BLK] = __uint_as_float((unsigned)w1); done |= 2u; }
            if (done == 3u) break;
            if (++guard > (1 << 18)) { bail = 1; break; }
            __builtin_amdgcn_s_sleep(1);
        }
    }
    __syncthreads();
}

// ---------------------------------------------------------------------------
// Persistent cooperative scan, 1024 threads (16 waves). wg w owns rows
// [8w,8w+8) of Wfh and Whf in LDS. Each row r is computed by wave-pair
// (2r, 2r+1): each wave half-dots 1024 elements, partials combined via LDS.
// Epochs: h0 tag=1; step t gathers tag t+1 (h then g), publishes g tag t+1
// and h tag t+2. 0xAA poison never matches an epoch -> no buffer init.
// Single-buffer safety: wg overwrites h_buf (tag t+2) only after consuming
// g (tag t+1), which requires all wgs published g, which requires all wgs
// completed their h-gather (tag t+1). Same chain as r3.
// ---------------------------------------------------------------------------
__global__ __launch_bounds__(SCAN_BLK) void mgu_scan(
    const float* __restrict__ h0,
    const float* __restrict__ Wfh,
    const float* __restrict__ Whf,
    const float* __restrict__ XF,
    const float* __restrict__ XH,
    float* __restrict__ y,
    float* __restrict__ hfin,
    ull* h_buf, ull* g_buf)
{
    extern __shared__ float smem[];
    float* wf    = smem;                     // ROWS*HDIM (Wfh rows)
    float* wh    = wf + ROWS * HDIM;         // ROWS*HDIM (Whf rows)
    float* h_lds = wh + ROWS * HDIM;         // HDIM
    float* g_lds = h_lds + HDIM;             // HDIM
    float* part  = g_lds + HDIM;             // 16 partials (one per wave)

    const int wg   = blockIdx.x;
    const int tid  = threadIdx.x;
    const int lane = tid & 63;
    const int wv   = tid >> 6;               // wave 0..15
    const int row  = wv >> 1;                // row 0..7 (2 waves per row)
    const int half = wv & 1;                 // which 1024-element half
    const int base = wg * ROWS;
    const bool owner = (half == 0) && (lane == 0);   // per-row owner lane

    // ---- one-time: stage this wg's weight rows into LDS (4 float4/thread/mat)
    for (int i = tid; i < ROWS * HDIM / 4; i += SCAN_BLK) {
        ((float4*)wf)[i] = ((const float4*)(Wfh + (size_t)base * HDIM))[i];
        ((float4*)wh)[i] = ((const float4*)(Whf + (size_t)base * HDIM))[i];
    }
    // ---- publish this wg's h0 slice, tag 1
    if (tid < ROWS)
        publish_tagged(h_buf, base + tid, 1u, h0[base + tid]);
    __syncthreads();

    int bail = 0;
    float f_r = 0.f, ho_r = 0.f;             // owner-lane state across phases

    for (int t = 0; t < S_LEN; ++t) {
        // per-row step constants (owner lanes; issued before the gather wait)
        float xf_r = 0.f, xh_r = 0.f;
        if (owner) {
            xf_r = XF[(size_t)t * HDIM + base + row];
            xh_r = XH[(size_t)t * HDIM + base + row];
        }

        // ---- phase A: gather h(t) (tag t+1) into LDS       [barrier #1]
        gather_tagged(h_buf, (unsigned)(t + 1), h_lds, tid, bail);

        // ---- matvec1 half-dot: row `row`, elements [half*1024, +1024)
        float4 a = {0, 0, 0, 0};
#pragma unroll
        for (int it = 0; it < 4; ++it) {
            int j = half * 1024 + it * 256 + (lane << 2);
            float4 hv = *(const float4*)&h_lds[j];
            float4 w0 = *(const float4*)&wf[row * HDIM + j];
            a.x = fmaf(w0.x, hv.x, a.x); a.y = fmaf(w0.y, hv.y, a.y);
            a.z = fmaf(w0.z, hv.z, a.z); a.w = fmaf(w0.w, hv.w, a.w);
        }
        float s = (a.x + a.y) + (a.z + a.w);
#pragma unroll
        for (int m = 32; m >= 1; m >>= 1) s += __shfl_xor(s, m);
        if (lane == 0) part[wv] = s;
        __syncthreads();                                     // barrier #2

        if (owner) {
            float tot = part[wv] + part[wv + 1];
            f_r  = 1.f / (1.f + expf(-(tot + xf_r)));
            ho_r = h_lds[base + row];                        // register-cache h_old
            publish_tagged(g_buf, base + row, (unsigned)(t + 1), f_r * ho_r);
        }

        // ---- phase B: gather g(t) (tag t+1) into LDS       [barrier #3]
        gather_tagged(g_buf, (unsigned)(t + 1), g_lds, tid, bail);

        // ---- matvec2 half-dot
        a = make_float4(0, 0, 0, 0);
#pragma unroll
        for (int it = 0; it < 4; ++it) {
            int j = half * 1024 + it * 256 + (lane << 2);
            float4 gv = *(const float4*)&g_lds[j];
            float4 w0 = *(const float4*)&wh[row * HDIM + j];
            a.x = fmaf(w0.x, gv.x, a.x); a.y = fmaf(w0.y, gv.y, a.y);
            a.z = fmaf(w0.z, gv.z, a.z); a.w = fmaf(w0.w, gv.w, a.w);
        }
        s = (a.x + a.y) + (a.z + a.w);
#pragma unroll
        for (int m = 32; m >= 1; m >>= 1) s += __shfl_xor(s, m);
        if (lane == 0) part[wv] = s;
        __syncthreads();                                     // barrier #4

        if (owner) {
            float tot = part[wv] + part[wv + 1];
            float hh  = tanhf(tot + xh_r);
            float hn  = ho_r + f_r * (hh - ho_r);            // (1-f)h + f*hhat
            y[(size_t)t * HDIM + base + row] = hn;
            publish_tagged(h_buf, base + row, (unsigned)(t + 2), hn);
            if (t == S_LEN - 1) hfin[base + row] = hn;
        }
        // no end-of-loop barrier: next h-gather overwrites h_lds only after
        // barrier #1 of the next iteration's... gather writes happen before
        // its closing barrier, but all h_lds readers of THIS step finished
        // before barrier #4, and part[] is rewritten only after next barrier #1.
    }
}

// ---------------------------------------------------------------------------
extern "C" void kernel_launch(void* const* d_in, const int* in_sizes, int n_in,
                              void* d_out, int out_size, void* d_ws, size_t ws_size,
                              hipStream_t stream)
{
    const float* x   = (const float*)d_in[0];
    const float* h0  = (const float*)d_in[1];
    const float* Wfx = (const float*)d_in[2];
    const float* bfx = (const float*)d_in[3];
    const float* Wfh = (const float*)d_in[4];
    const float* bfh = (const float*)d_in[5];
    const float* Whf = (const float*)d_in[6];
    const float* bhf = (const float*)d_in[7];
    const float* Whx = (const float*)d_in[8];
    const float* bhx = (const float*)d_in[9];

    float* y    = (float*)d_out;
    float* hfin = y + (size_t)S_LEN * HDIM;

    // workspace layout (tags self-validate vs 0xAA poison -> no memset needed)
    float* XF  = (float*)d_ws;
    float* XH  = XF + (size_t)S_LEN * HDIM;
    ull* h_buf = (ull*)(XH + (size_t)S_LEN * HDIM);
    ull* g_buf = h_buf + HDIM;

    // phase 1: input projections (biases folded: XF += bfx+bfh, XH += bhx+bhf)
    dim3 gg(HDIM / 64, S_LEN / 64, 2);
    xproj_gemm<<<gg, 256, 0, stream>>>(x, Wfx, bfx, bfh, Whx, bhx, bhf, XF, XH);

    // phase 2: cooperative persistent scan (≈144 KiB dynamic LDS -> 1 wg/CU)
    const int smem_bytes = (2 * ROWS * HDIM + 2 * HDIM + 16) * (int)sizeof(float);
    hipFuncSetAttribute((const void*)mgu_scan,
                        hipFuncAttributeMaxDynamicSharedMemorySize, smem_bytes);

    void* args[] = {(void*)&h0, (void*)&Wfh, (void*)&Whf, (void*)&XF, (void*)&XH,
                    (void*)&y, (void*)&hfin, (void*)&h_buf, (void*)&g_buf};
    hipError_t err = hipLaunchCooperativeKernel((void*)mgu_scan, dim3(NWG), dim3(SCAN_BLK),
                                                args, (unsigned)smem_bytes, stream);
    if (err != hipSuccess) {
        // fallback: plain launch (grid == CU count, 1 wg/CU -> co-resident;
        // bail guards prevent a hard hang if co-residency fails)
        mgu_scan<<<dim3(NWG), dim3(SCAN_BLK), smem_bytes, stream>>>(
            h0, Wfh, Whf, XF, XH, y, hfin, h_buf, g_buf);
    }
}